// Round 1
// baseline (334.774 us; speedup 1.0000x reference)
//
#include <hip/hip_runtime.h>
#include <hip/hip_bf16.h>
#include <math.h>

typedef unsigned short ushort_t;
typedef __attribute__((ext_vector_type(8))) short bf16x8;   // 8 bf16 = 4 VGPRs
typedef __attribute__((ext_vector_type(4))) float f32x4;

#define AS1 __attribute__((address_space(1)))
#define AS3 __attribute__((address_space(3)))

__device__ __forceinline__ void gld_lds16(const void* g, void* l) {
  // async global->LDS, 16B per lane; LDS dest = wave-uniform base + lane*16
  __builtin_amdgcn_global_load_lds((const AS1 void*)g, (AS3 void*)l, 16, 0, 0);
}

__device__ __forceinline__ ushort_t f32_to_bf16_bits(float v) {
  __hip_bfloat16 b = __float2bfloat16(v);
  return *(ushort_t*)&b;
}

// ---------------- row L2-normalize (fp32 in -> bf16 out) ----------------
__global__ void normalize_rows(const float* __restrict__ x, ushort_t* __restrict__ o, int D) {
  const int row = blockIdx.x;
  const float* xr = x + (size_t)row * D;
  float ss = 0.f;
  for (int i = threadIdx.x; i < D; i += 256) { float v = xr[i]; ss += v * v; }
#pragma unroll
  for (int off = 32; off > 0; off >>= 1) ss += __shfl_down(ss, off, 64);
  __shared__ float part[4];
  if ((threadIdx.x & 63) == 0) part[threadIdx.x >> 6] = ss;
  __syncthreads();
  float tot = part[0] + part[1] + part[2] + part[3];
  float scale = 1.0f / fmaxf(sqrtf(tot), 1e-12f);
  ushort_t* orow = o + (size_t)row * D;
  for (int i = threadIdx.x; i < D; i += 256) orow[i] = f32_to_bf16_bits(xr[i] * scale);
}

// ------------- transpose prototype_class [K,C] f32 -> [CP,K] bf16 (pad cols>=C with 0) -------------
__global__ void transpose_pc(const float* __restrict__ pc, ushort_t* __restrict__ pcT,
                             int K, int C) {
  __shared__ float tile[32][33];
  int k = blockIdx.x * 32 + threadIdx.y;
  int n = blockIdx.y * 32 + threadIdx.x;
  tile[threadIdx.y][threadIdx.x] = (n < C) ? pc[(size_t)k * C + n] : 0.f;
  __syncthreads();
  int nn = blockIdx.y * 32 + threadIdx.y;
  int kk = blockIdx.x * 32 + threadIdx.x;
  pcT[(size_t)nn * K + kk] = f32_to_bf16_bits(tile[threadIdx.x][threadIdx.y]);
}

// ---------------- 128x128-tile bf16 MFMA GEMM, B^T layout ----------------
// MODE 0: epilogue act = exp(-tau*sqrt(max(2-2*dot,0))), store bf16, ldc=N
// MODE 1: plain fp32 store with col < ncols guard
template <int MODE>
__launch_bounds__(256)
__global__ void gemm_bt(const ushort_t* __restrict__ A, const ushort_t* __restrict__ B,
                        void* __restrict__ Cout, const float* __restrict__ tptr,
                        int K, int ldc, int ncols) {
  __shared__ __align__(16) ushort_t As[128 * 32];
  __shared__ __align__(16) ushort_t Bs[128 * 32];
  const int tid = threadIdx.x;
  const int lane = tid & 63;
  const int wave = tid >> 6;
  const int wm = wave >> 1, wn = wave & 1;      // 2x2 wave grid, 64x64 each
  const int rowBase = blockIdx.y * 128;
  const int colBase = blockIdx.x * 128;

  f32x4 acc[4][4];
#pragma unroll
  for (int i = 0; i < 4; ++i)
#pragma unroll
    for (int j = 0; j < 4; ++j) acc[i][j] = (f32x4){0.f, 0.f, 0.f, 0.f};

  // staging: each wave covers 16 rows per call (64 lanes * 16B = 16 rows of 64B)
  const int lrow = lane >> 2;       // 0..15
  const int lcol = (lane & 3) * 8;  // bf16 elems: 0,8,16,24
  const size_t aOff = (size_t)(rowBase + wave * 16 + lrow) * K + lcol;
  const size_t bOff = (size_t)(colBase + wave * 16 + lrow) * K + lcol;
  const size_t stride64 = (size_t)64 * K;
  ushort_t* ldsA0 = &As[(wave * 16) * 32];
  ushort_t* ldsA1 = &As[(64 + wave * 16) * 32];
  ushort_t* ldsB0 = &Bs[(wave * 16) * 32];
  ushort_t* ldsB1 = &Bs[(64 + wave * 16) * 32];

  const int fr = lane & 15;         // fragment row (A) / col (B)
  const int fk = (lane >> 4) * 8;   // fragment k offset

  const int nK = K >> 5;
  for (int kt = 0; kt < nK; ++kt) {
    const int kb = kt << 5;
    __syncthreads();  // previous tile's LDS reads done
    gld_lds16(A + aOff + kb, ldsA0);
    gld_lds16(A + aOff + stride64 + kb, ldsA1);
    gld_lds16(B + bOff + kb, ldsB0);
    gld_lds16(B + bOff + stride64 + kb, ldsB1);
    __syncthreads();  // staging complete (vmcnt drained before barrier)

    bf16x8 af[4], bfr[4];
#pragma unroll
    for (int i = 0; i < 4; ++i)
      af[i] = *(const bf16x8*)&As[(wm * 64 + i * 16 + fr) * 32 + fk];
#pragma unroll
    for (int j = 0; j < 4; ++j)
      bfr[j] = *(const bf16x8*)&Bs[(wn * 64 + j * 16 + fr) * 32 + fk];
#pragma unroll
    for (int i = 0; i < 4; ++i)
#pragma unroll
      for (int j = 0; j < 4; ++j)
        acc[i][j] = __builtin_amdgcn_mfma_f32_16x16x32_bf16(af[i], bfr[j], acc[i][j], 0, 0, 0);
  }

  float tau = 0.f;
  if (MODE == 0) { float t = *tptr; tau = log1pf(expf(t)); }

  // C/D layout: col = lane&15, row = (lane>>4)*4 + reg   [measured m89/m91]
  const int crow = (lane >> 4) * 4;
  const int ccol = lane & 15;
#pragma unroll
  for (int i = 0; i < 4; ++i) {
#pragma unroll
    for (int j = 0; j < 4; ++j) {
      const int col = colBase + wn * 64 + j * 16 + ccol;
#pragma unroll
      for (int r = 0; r < 4; ++r) {
        const int row = rowBase + wm * 64 + i * 16 + crow + r;
        float v = acc[i][j][r];
        if (MODE == 0) {
          float d2 = fmaxf(2.0f - 2.0f * v, 0.0f);
          float act = __expf(-tau * sqrtf(d2));
          ((ushort_t*)Cout)[(size_t)row * ldc + col] = f32_to_bf16_bits(act);
        } else {
          if (col < ncols)
            ((float*)Cout)[(size_t)row * ldc + col] = v;
        }
      }
    }
  }
}

extern "C" void kernel_launch(void* const* d_in, const int* in_sizes, int n_in,
                              void* d_out, int out_size, void* d_ws, size_t ws_size,
                              hipStream_t stream) {
  const float* h    = (const float*)d_in[0];
  const float* prot = (const float*)d_in[1];
  const float* pc   = (const float*)d_in[2];
  const float* temp = (const float*)d_in[3];
  float* out = (float*)d_out;

  const int D = 768;
  const int N = in_sizes[0] / D;          // 16384
  const int P = in_sizes[1] / D;          // 2048
  const int C = in_sizes[2] / P;          // 1000
  const int CP = (C + 127) & ~127;        // 1024 (padded)

  // workspace layout (bf16 buffers, 16B aligned)
  char* ws = (char*)d_ws;
  size_t off = 0;
  ushort_t* hN  = (ushort_t*)(ws + off); off += (size_t)N * D * 2;    // 25.2 MB
  ushort_t* pN  = (ushort_t*)(ws + off); off += (size_t)P * D * 2;    //  3.1 MB
  ushort_t* pcT = (ushort_t*)(ws + off); off += (size_t)CP * P * 2;   //  4.2 MB
  ushort_t* act = (ushort_t*)(ws + off); off += (size_t)N * P * 2;    // 67.1 MB
  (void)ws_size;  // total ~99.6 MB

  normalize_rows<<<N, 256, 0, stream>>>(h, hN, D);
  normalize_rows<<<P, 256, 0, stream>>>(prot, pN, D);
  transpose_pc<<<dim3(P / 32, CP / 32), dim3(32, 32), 0, stream>>>(pc, pcT, P, C);

  // GEMM1: [N,P] = hN[N,D] @ pN[P,D]^T, fused distance/exp epilogue -> act bf16
  gemm_bt<0><<<dim3(P / 128, N / 128), 256, 0, stream>>>(hN, pN, act, temp, D, P, P);
  // GEMM2: [N,C] = act[N,P] @ pcT[CP,P]^T -> fp32 out (col guard at C)
  gemm_bt<1><<<dim3(CP / 128, N / 128), 256, 0, stream>>>(act, pcT, out, nullptr, P, C, C);
}

// Round 2
// 301.590 us; speedup vs baseline: 1.1100x; 1.1100x over previous
//
#include <hip/hip_runtime.h>
#include <hip/hip_bf16.h>
#include <math.h>

typedef unsigned short ushort_t;
typedef unsigned int uint_t;
typedef __attribute__((ext_vector_type(8))) short bf16x8;   // 8 bf16 = 4 VGPRs
typedef __attribute__((ext_vector_type(4))) float f32x4;

#define AS1 __attribute__((address_space(1)))
#define AS3 __attribute__((address_space(3)))

__device__ __forceinline__ void gld_lds16(const void* g, void* l) {
  // async global->LDS, 16B per lane; LDS dest = wave-uniform base + lane*16
  __builtin_amdgcn_global_load_lds((const AS1 void*)g, (AS3 void*)l, 16, 0, 0);
}

__device__ __forceinline__ ushort_t f32_to_bf16_bits(float v) {
  __hip_bfloat16 b = __float2bfloat16(v);
  return *(ushort_t*)&b;
}

__device__ __forceinline__ uint_t pack_bf16x2(float lo, float hi) {
  return (uint_t)f32_to_bf16_bits(lo) | ((uint_t)f32_to_bf16_bits(hi) << 16);
}

// ---------------- wave-per-row L2-normalize (fp32 in -> bf16 out), D=768 ----------------
// float4 loads (3/lane), shfl-xor reduce, uint2-packed bf16 stores. No LDS, no syncthreads.
__global__ __launch_bounds__(256) void normalize_rows_w(const float4* __restrict__ x,
                                                        uint2* __restrict__ o, int rows) {
  const int gwave = (blockIdx.x * 256 + threadIdx.x) >> 6;
  const int lane = threadIdx.x & 63;
  if (gwave >= rows) return;
  const float4* xr = x + (size_t)gwave * 192;   // 768 floats = 192 float4
  float4 v0 = xr[lane];
  float4 v1 = xr[lane + 64];
  float4 v2 = xr[lane + 128];
  float ss = v0.x * v0.x + v0.y * v0.y + v0.z * v0.z + v0.w * v0.w
           + v1.x * v1.x + v1.y * v1.y + v1.z * v1.z + v1.w * v1.w
           + v2.x * v2.x + v2.y * v2.y + v2.z * v2.z + v2.w * v2.w;
#pragma unroll
  for (int off = 32; off > 0; off >>= 1) ss += __shfl_xor(ss, off, 64);
  const float scale = 1.0f / fmaxf(sqrtf(ss), 1e-12f);
  uint2* orow = o + (size_t)gwave * 192;        // 768 bf16 = 192 uint2
  orow[lane]       = make_uint2(pack_bf16x2(v0.x * scale, v0.y * scale),
                                pack_bf16x2(v0.z * scale, v0.w * scale));
  orow[lane + 64]  = make_uint2(pack_bf16x2(v1.x * scale, v1.y * scale),
                                pack_bf16x2(v1.z * scale, v1.w * scale));
  orow[lane + 128] = make_uint2(pack_bf16x2(v2.x * scale, v2.y * scale),
                                pack_bf16x2(v2.z * scale, v2.w * scale));
}

// ------------- transpose prototype_class [K,C] f32 -> [CP,K] bf16 (pad cols>=C with 0) -------------
__global__ void transpose_pc(const float* __restrict__ pc, ushort_t* __restrict__ pcT,
                             int K, int C) {
  __shared__ float tile[32][33];
  int k = blockIdx.x * 32 + threadIdx.y;
  int n = blockIdx.y * 32 + threadIdx.x;
  tile[threadIdx.y][threadIdx.x] = (n < C) ? pc[(size_t)k * C + n] : 0.f;
  __syncthreads();
  int nn = blockIdx.y * 32 + threadIdx.y;
  int kk = blockIdx.x * 32 + threadIdx.x;
  pcT[(size_t)nn * K + kk] = f32_to_bf16_bits(tile[threadIdx.x][threadIdx.y]);
}

// ---------------- 128x128-tile bf16 MFMA GEMM, B^T layout, XCD-swizzled 1D grid ----------------
// Logical tiles (s = row-stripe in [0,GY), t = col-tile in [0,GX)) are remapped so all
// GX col-tiles of stripe s get linear block ids congruent to s (mod 8) -> same XCD,
// temporally adjacent. Per-XCD L2 then holds the A-stripe + the full B panel.
//   lid = (s & 7) | ((t + GX * (s >> 3)) << 3)       [requires 8 | GY]
// MODE 0: epilogue act = exp(-tau*sqrt(max(2-2*dot,0))), store bf16, ldc=P
// MODE 1: plain fp32 store with col < ncols guard
template <int MODE>
__launch_bounds__(256)
__global__ void gemm_bt(const ushort_t* __restrict__ A, const ushort_t* __restrict__ B,
                        void* __restrict__ Cout, const float* __restrict__ tptr,
                        int K, int ldc, int ncols, int gx, int gxlog2) {
  __shared__ __align__(16) ushort_t As[128 * 32];
  __shared__ __align__(16) ushort_t Bs[128 * 32];
  const int tid = threadIdx.x;
  const int lane = tid & 63;
  const int wave = tid >> 6;
  const int wm = wave >> 1, wn = wave & 1;      // 2x2 wave grid, 64x64 each

  // de-swizzle linear block id -> (s, t)
  const int lid = blockIdx.x;
  const int xcd = lid & 7;
  const int q = lid >> 3;
  const int t = q & (gx - 1);
  const int s = ((q >> gxlog2) << 3) | xcd;
  const int rowBase = s * 128;
  const int colBase = t * 128;

  f32x4 acc[4][4];
#pragma unroll
  for (int i = 0; i < 4; ++i)
#pragma unroll
    for (int j = 0; j < 4; ++j) acc[i][j] = (f32x4){0.f, 0.f, 0.f, 0.f};

  // staging: each wave covers 16 rows per call (64 lanes * 16B = 16 rows of 64B)
  const int lrow = lane >> 2;       // 0..15
  const int lcol = (lane & 3) * 8;  // bf16 elems: 0,8,16,24
  const size_t aOff = (size_t)(rowBase + wave * 16 + lrow) * K + lcol;
  const size_t bOff = (size_t)(colBase + wave * 16 + lrow) * K + lcol;
  const size_t stride64 = (size_t)64 * K;
  ushort_t* ldsA0 = &As[(wave * 16) * 32];
  ushort_t* ldsA1 = &As[(64 + wave * 16) * 32];
  ushort_t* ldsB0 = &Bs[(wave * 16) * 32];
  ushort_t* ldsB1 = &Bs[(64 + wave * 16) * 32];

  const int fr = lane & 15;         // fragment row (A) / col (B)
  const int fk = (lane >> 4) * 8;   // fragment k offset

  const int nK = K >> 5;
  for (int kt = 0; kt < nK; ++kt) {
    const int kb = kt << 5;
    __syncthreads();  // previous tile's LDS reads done
    gld_lds16(A + aOff + kb, ldsA0);
    gld_lds16(A + aOff + stride64 + kb, ldsA1);
    gld_lds16(B + bOff + kb, ldsB0);
    gld_lds16(B + bOff + stride64 + kb, ldsB1);
    __syncthreads();  // staging complete (vmcnt drained before barrier)

    bf16x8 af[4], bfr[4];
#pragma unroll
    for (int i = 0; i < 4; ++i)
      af[i] = *(const bf16x8*)&As[(wm * 64 + i * 16 + fr) * 32 + fk];
#pragma unroll
    for (int j = 0; j < 4; ++j)
      bfr[j] = *(const bf16x8*)&Bs[(wn * 64 + j * 16 + fr) * 32 + fk];
#pragma unroll
    for (int i = 0; i < 4; ++i)
#pragma unroll
      for (int j = 0; j < 4; ++j)
        acc[i][j] = __builtin_amdgcn_mfma_f32_16x16x32_bf16(af[i], bfr[j], acc[i][j], 0, 0, 0);
  }

  float tau = 0.f;
  if (MODE == 0) { float tmp = *tptr; tau = log1pf(expf(tmp)); }

  // C/D layout: col = lane&15, row = (lane>>4)*4 + reg   [measured m89/m91]
  const int crow = (lane >> 4) * 4;
  const int ccol = lane & 15;
#pragma unroll
  for (int i = 0; i < 4; ++i) {
#pragma unroll
    for (int j = 0; j < 4; ++j) {
      const int col = colBase + wn * 64 + j * 16 + ccol;
#pragma unroll
      for (int r = 0; r < 4; ++r) {
        const int row = rowBase + wm * 64 + i * 16 + crow + r;
        float v = acc[i][j][r];
        if (MODE == 0) {
          float d2 = fmaxf(2.0f - 2.0f * v, 0.0f);
          float act = __expf(-tau * sqrtf(d2));
          ((ushort_t*)Cout)[(size_t)row * ldc + col] = f32_to_bf16_bits(act);
        } else {
          if (col < ncols)
            ((float*)Cout)[(size_t)row * ldc + col] = v;
        }
      }
    }
  }
}

extern "C" void kernel_launch(void* const* d_in, const int* in_sizes, int n_in,
                              void* d_out, int out_size, void* d_ws, size_t ws_size,
                              hipStream_t stream) {
  const float* h    = (const float*)d_in[0];
  const float* prot = (const float*)d_in[1];
  const float* pc   = (const float*)d_in[2];
  const float* temp = (const float*)d_in[3];
  float* out = (float*)d_out;

  const int D = 768;
  const int N = in_sizes[0] / D;          // 16384
  const int P = in_sizes[1] / D;          // 2048
  const int C = in_sizes[2] / P;          // 1000
  const int CP = (C + 127) & ~127;        // 1024 (padded)

  // workspace layout (bf16 buffers, 16B aligned)
  char* ws = (char*)d_ws;
  size_t off = 0;
  ushort_t* hN  = (ushort_t*)(ws + off); off += (size_t)N * D * 2;    // 25.2 MB
  ushort_t* pN  = (ushort_t*)(ws + off); off += (size_t)P * D * 2;    //  3.1 MB
  ushort_t* pcT = (ushort_t*)(ws + off); off += (size_t)CP * P * 2;   //  4.2 MB
  ushort_t* act = (ushort_t*)(ws + off); off += (size_t)N * P * 2;    // 67.1 MB
  (void)ws_size;  // total ~99.6 MB

  // wave-per-row normalize: 4 rows per 256-thread block
  normalize_rows_w<<<N / 4, 256, 0, stream>>>((const float4*)h, (uint2*)hN, N);
  normalize_rows_w<<<P / 4, 256, 0, stream>>>((const float4*)prot, (uint2*)pN, P);
  transpose_pc<<<dim3(P / 32, CP / 32), dim3(32, 32), 0, stream>>>(pc, pcT, P, C);

  // GEMM1: [N,P] = hN[N,D] @ pN[P,D]^T, fused distance/exp epilogue -> act bf16
  {
    const int GX = P / 128, GY = N / 128;   // 16, 128
    gemm_bt<0><<<GX * GY, 256, 0, stream>>>(hN, pN, act, temp, D, P, P, GX, 4);
  }
  // GEMM2: [N,C] = act[N,P] @ pcT[CP,P]^T -> fp32 out (col guard at C)
  {
    const int GX = CP / 128, GY = N / 128;  // 8, 128
    gemm_bt<1><<<GX * GY, 256, 0, stream>>>(act, pcT, out, nullptr, P, C, C, GX, 3);
  }
}

// Round 3
// 298.792 us; speedup vs baseline: 1.1204x; 1.0094x over previous
//
#include <hip/hip_runtime.h>
#include <hip/hip_bf16.h>
#include <math.h>

typedef unsigned short ushort_t;
typedef unsigned int uint_t;
typedef __attribute__((ext_vector_type(8))) short bf16x8;   // 8 bf16 = 4 VGPRs
typedef __attribute__((ext_vector_type(4))) float f32x4;

#define AS1 __attribute__((address_space(1)))
#define AS3 __attribute__((address_space(3)))

__device__ __forceinline__ void gld_lds16(const void* g, void* l) {
  // async global->LDS, 16B per lane; LDS dest = wave-uniform base + lane*16
  __builtin_amdgcn_global_load_lds((const AS1 void*)g, (AS3 void*)l, 16, 0, 0);
}

__device__ __forceinline__ ushort_t f32_to_bf16_bits(float v) {
  __hip_bfloat16 b = __float2bfloat16(v);
  return *(ushort_t*)&b;
}

__device__ __forceinline__ uint_t pack_bf16x2(float lo, float hi) {
  return (uint_t)f32_to_bf16_bits(lo) | ((uint_t)f32_to_bf16_bits(hi) << 16);
}

// ------------- fused wave-per-row L2-normalize for h and prototypes (D=768) -------------
// float4 loads (3/lane), shfl-xor reduce, uint2-packed bf16 stores. No LDS, no syncthreads.
__global__ __launch_bounds__(256) void normalize_rows_w(const float4* __restrict__ x1,
                                                        uint2* __restrict__ o1, int rows1,
                                                        const float4* __restrict__ x2,
                                                        uint2* __restrict__ o2, int rows2) {
  int gwave = (blockIdx.x * 256 + threadIdx.x) >> 6;
  const int lane = threadIdx.x & 63;
  const float4* xr;
  uint2* orow;
  if (gwave < rows1) {
    xr = x1 + (size_t)gwave * 192;          // 768 floats = 192 float4
    orow = o1 + (size_t)gwave * 192;        // 768 bf16 = 192 uint2
  } else {
    gwave -= rows1;
    if (gwave >= rows2) return;
    xr = x2 + (size_t)gwave * 192;
    orow = o2 + (size_t)gwave * 192;
  }
  float4 v0 = xr[lane];
  float4 v1 = xr[lane + 64];
  float4 v2 = xr[lane + 128];
  float ss = v0.x * v0.x + v0.y * v0.y + v0.z * v0.z + v0.w * v0.w
           + v1.x * v1.x + v1.y * v1.y + v1.z * v1.z + v1.w * v1.w
           + v2.x * v2.x + v2.y * v2.y + v2.z * v2.z + v2.w * v2.w;
#pragma unroll
  for (int off = 32; off > 0; off >>= 1) ss += __shfl_xor(ss, off, 64);
  const float scale = 1.0f / fmaxf(sqrtf(ss), 1e-12f);
  orow[lane]       = make_uint2(pack_bf16x2(v0.x * scale, v0.y * scale),
                                pack_bf16x2(v0.z * scale, v0.w * scale));
  orow[lane + 64]  = make_uint2(pack_bf16x2(v1.x * scale, v1.y * scale),
                                pack_bf16x2(v1.z * scale, v1.w * scale));
  orow[lane + 128] = make_uint2(pack_bf16x2(v2.x * scale, v2.y * scale),
                                pack_bf16x2(v2.z * scale, v2.w * scale));
}

// ------------- transpose prototype_class [K,C] f32 -> [CP,K] bf16 (pad cols>=C with 0) -------------
__global__ void transpose_pc(const float* __restrict__ pc, ushort_t* __restrict__ pcT,
                             int K, int C) {
  __shared__ float tile[32][33];
  int k = blockIdx.x * 32 + threadIdx.y;
  int n = blockIdx.y * 32 + threadIdx.x;
  tile[threadIdx.y][threadIdx.x] = (n < C) ? pc[(size_t)k * C + n] : 0.f;
  __syncthreads();
  int nn = blockIdx.y * 32 + threadIdx.y;
  int kk = blockIdx.x * 32 + threadIdx.x;
  pcT[(size_t)nn * K + kk] = f32_to_bf16_bits(tile[threadIdx.x][threadIdx.y]);
}

// ---------------- 128x128-tile bf16 MFMA GEMM, B^T layout, XCD-swizzled 1D grid ----------------
// XCD swizzle: all GX col-tiles of row-stripe s get block ids == s (mod 8) -> same XCD,
// temporally adjacent; per-XCD L2 holds the A-stripe + full B panel. [R1: FETCH 268->58 MB]
// LDS XOR swizzle: lane loads global k-chunk (l&3)^((l>>3)&3) into its fixed
// global_load_lds slot; reads use physical chunk (lane>>4)^((fr>>1)&3). Breaks the
// 8-way ds_read_b128 bank conflict (64 B row stride) down to free 2-way. [R3]
// MODE 0: epilogue act = exp(-tau*sqrt(max(2-2*dot,0))), LDS-staged coalesced bf16 store
// MODE 1: plain fp32 store with col < ncols guard
template <int MODE>
__launch_bounds__(256)
__global__ void gemm_bt(const ushort_t* __restrict__ A, const ushort_t* __restrict__ B,
                        void* __restrict__ Cout, const float* __restrict__ tptr,
                        int K, int ldc, int ncols, int gx, int gxlog2) {
  __shared__ __align__(16) ushort_t smem[2 * 128 * 32];   // As | Bs; reused by epilogue
  ushort_t* As = smem;
  ushort_t* Bs = smem + 128 * 32;
  const int tid = threadIdx.x;
  const int lane = tid & 63;
  const int wave = tid >> 6;
  const int wm = wave >> 1, wn = wave & 1;      // 2x2 wave grid, 64x64 each

  // de-swizzle linear block id -> (s, t)
  const int lid = blockIdx.x;
  const int xcd = lid & 7;
  const int q = lid >> 3;
  const int t = q & (gx - 1);
  const int s = ((q >> gxlog2) << 3) | xcd;
  const int rowBase = s * 128;
  const int colBase = t * 128;

  f32x4 acc[4][4];
#pragma unroll
  for (int i = 0; i < 4; ++i)
#pragma unroll
    for (int j = 0; j < 4; ++j) acc[i][j] = (f32x4){0.f, 0.f, 0.f, 0.f};

  // staging: each wave covers 16 rows per call (64 lanes * 16B = 16 rows of 64B)
  const int lrow = lane >> 2;                        // 0..15
  const int lchunk = (lane & 3) ^ ((lane >> 3) & 3); // XOR-swizzled global 16B chunk
  const int lcol = lchunk * 8;                       // ushort offset 0/8/16/24
  const size_t aOff = (size_t)(rowBase + wave * 16 + lrow) * K + lcol;
  const size_t bOff = (size_t)(colBase + wave * 16 + lrow) * K + lcol;
  const size_t stride64 = (size_t)64 * K;
  ushort_t* ldsA0 = &As[(wave * 16) * 32];
  ushort_t* ldsA1 = &As[(64 + wave * 16) * 32];
  ushort_t* ldsB0 = &Bs[(wave * 16) * 32];
  ushort_t* ldsB1 = &Bs[(64 + wave * 16) * 32];

  const int fr = lane & 15;                             // fragment row (A) / col (B)
  const int fkp = ((lane >> 4) ^ ((fr >> 1) & 3)) * 8;  // physical chunk after swizzle

  const int nK = K >> 5;
  for (int kt = 0; kt < nK; ++kt) {
    const int kb = kt << 5;
    __syncthreads();  // previous tile's LDS reads done
    gld_lds16(A + aOff + kb, ldsA0);
    gld_lds16(A + aOff + stride64 + kb, ldsA1);
    gld_lds16(B + bOff + kb, ldsB0);
    gld_lds16(B + bOff + stride64 + kb, ldsB1);
    __syncthreads();  // staging complete (vmcnt drained before barrier)

    bf16x8 af[4], bfr[4];
#pragma unroll
    for (int i = 0; i < 4; ++i)
      af[i] = *(const bf16x8*)&As[(wm * 64 + i * 16 + fr) * 32 + fkp];
#pragma unroll
    for (int j = 0; j < 4; ++j)
      bfr[j] = *(const bf16x8*)&Bs[(wn * 64 + j * 16 + fr) * 32 + fkp];
#pragma unroll
    for (int i = 0; i < 4; ++i)
#pragma unroll
      for (int j = 0; j < 4; ++j)
        acc[i][j] = __builtin_amdgcn_mfma_f32_16x16x32_bf16(af[i], bfr[j], acc[i][j], 0, 0, 0);
  }

  // C/D layout: col = lane&15, row = (lane>>4)*4 + reg   [measured m89/m91]
  const int crow = (lane >> 4) * 4;
  const int ccol = lane & 15;

  if (MODE == 0) {
    float tmp = *tptr;
    const float tau = log1pf(expf(tmp));
    // stage act tile through LDS in two 64-row halves -> 256 B-contiguous stores
#pragma unroll
    for (int half = 0; half < 2; ++half) {
      __syncthreads();  // K-loop (or previous half's) smem reads done
      if (wm == half) {
#pragma unroll
        for (int i = 0; i < 4; ++i)
#pragma unroll
          for (int j = 0; j < 4; ++j)
#pragma unroll
            for (int r = 0; r < 4; ++r) {
              float v = acc[i][j][r];
              float d2 = fmaxf(2.0f - 2.0f * v, 0.0f);
              float act = __expf(-tau * sqrtf(d2));
              smem[(i * 16 + crow + r) * 128 + wn * 64 + j * 16 + ccol] =
                  f32_to_bf16_bits(act);
            }
      }
      __syncthreads();
      const int c16 = tid & 15;
      const int r0 = tid >> 4;  // 0..15
#pragma unroll
      for (int it = 0; it < 4; ++it) {
        const int row = r0 + it * 16;
        uint4 v = ((const uint4*)smem)[row * 16 + c16];
        *(uint4*)&((ushort_t*)Cout)[(size_t)(rowBase + half * 64 + row) * ldc +
                                    colBase + c16 * 8] = v;
      }
    }
  } else {
#pragma unroll
    for (int i = 0; i < 4; ++i) {
#pragma unroll
      for (int j = 0; j < 4; ++j) {
        const int col = colBase + wn * 64 + j * 16 + ccol;
#pragma unroll
        for (int r = 0; r < 4; ++r) {
          const int row = rowBase + wm * 64 + i * 16 + crow + r;
          if (col < ncols)
            ((float*)Cout)[(size_t)row * ldc + col] = acc[i][j][r];
        }
      }
    }
  }
}

extern "C" void kernel_launch(void* const* d_in, const int* in_sizes, int n_in,
                              void* d_out, int out_size, void* d_ws, size_t ws_size,
                              hipStream_t stream) {
  const float* h    = (const float*)d_in[0];
  const float* prot = (const float*)d_in[1];
  const float* pc   = (const float*)d_in[2];
  const float* temp = (const float*)d_in[3];
  float* out = (float*)d_out;

  const int D = 768;
  const int N = in_sizes[0] / D;          // 16384
  const int P = in_sizes[1] / D;          // 2048
  const int C = in_sizes[2] / P;          // 1000
  const int CP = (C + 127) & ~127;        // 1024 (padded)

  // workspace layout (bf16 buffers, 16B aligned)
  char* ws = (char*)d_ws;
  size_t off = 0;
  ushort_t* hN  = (ushort_t*)(ws + off); off += (size_t)N * D * 2;    // 25.2 MB
  ushort_t* pN  = (ushort_t*)(ws + off); off += (size_t)P * D * 2;    //  3.1 MB
  ushort_t* pcT = (ushort_t*)(ws + off); off += (size_t)CP * P * 2;   //  4.2 MB
  ushort_t* act = (ushort_t*)(ws + off); off += (size_t)N * P * 2;    // 67.1 MB
  (void)ws_size;  // total ~99.6 MB

  // fused wave-per-row normalize: 4 rows per 256-thread block, h then prototypes
  normalize_rows_w<<<(N + P) / 4, 256, 0, stream>>>((const float4*)h, (uint2*)hN, N,
                                                    (const float4*)prot, (uint2*)pN, P);
  transpose_pc<<<dim3(P / 32, CP / 32), dim3(32, 32), 0, stream>>>(pc, pcT, P, C);

  // GEMM1: [N,P] = hN[N,D] @ pN[P,D]^T, fused distance/exp epilogue -> act bf16
  {
    const int GX = P / 128, GY = N / 128;   // 16, 128
    gemm_bt<0><<<GX * GY, 256, 0, stream>>>(hN, pN, act, temp, D, P, P, GX, 4);
  }
  // GEMM2: [N,C] = act[N,P] @ pcT[CP,P]^T -> fp32 out (col guard at C)
  {
    const int GX = CP / 128, GY = N / 128;  // 8, 128
    gemm_bt<1><<<GX * GY, 256, 0, stream>>>(act, pcT, out, nullptr, P, C, C, GX, 3);
  }
}